// Round 11
// baseline (137.649 us; speedup 1.0000x reference)
//
#include <hip/hip_runtime.h>
#include <hip/hip_bf16.h>

// REN forward: BATCH=32768, N_X=64, N_UNITS=256, N_Y=32, N_U=64
typedef __attribute__((ext_vector_type(8))) short short8;
typedef __attribute__((ext_vector_type(4))) float floatx4;
typedef __attribute__((ext_vector_type(2))) float floatx2;

#define MFMA16 __builtin_amdgcn_mfma_f32_16x16x32_bf16

__device__ inline unsigned short bf16_rn(float f) {
    return (unsigned short)((__float_as_uint(f) + 0x8000u) >> 16);
}
// Packed f32->bf16 (RNE), value-based: no address-taken private arrays.
__device__ __attribute__((always_inline)) inline short8 pack8v(float4 a, float4 b) {
    union { short8 s; unsigned int u[4]; } r;
    union { __hip_bfloat162 h; unsigned int u; } c;
    c.h = __float22bfloat162_rn(make_float2(a.x, a.y)); r.u[0] = c.u;
    c.h = __float22bfloat162_rn(make_float2(a.z, a.w)); r.u[1] = c.u;
    c.h = __float22bfloat162_rn(make_float2(b.x, b.y)); r.u[2] = c.u;
    c.h = __float22bfloat162_rn(make_float2(b.z, b.w)); r.u[3] = c.u;
    return r.s;
}

// ---------------------------------------------------------------------------
// Prep13: (unchanged)
// ---------------------------------------------------------------------------
__global__ __launch_bounds__(64) void ren_prep13(
    const float* __restrict__ B2, const float* __restrict__ C2,
    const float* __restrict__ D12, const float* __restrict__ D21,
    const float* __restrict__ St, const float* __restrict__ Q,
    const float* __restrict__ Rinv,
    float* __restrict__ lT1, float* __restrict__ t1,
    float* __restrict__ lT2, float* __restrict__ t2,
    unsigned short* __restrict__ Wvb, unsigned short* __restrict__ C2b,
    unsigned short* __restrict__ D21b)
{
    const int t = threadIdx.x;
    const int blk = blockIdx.x;
    if (blk >= 384) {   // bf16-copy role (uniform branch)
        const int id = (blk - 384) * 64 + t;
        if (id < 16384) {
            Wvb[(id >> 6) * 128 + 64 + (id & 63)] = bf16_rn(D12[id]);
        } else if (id < 16384 + 2048) {
            C2b[id - 16384] = bf16_rn(C2[id - 16384]);
        } else if (id < 16384 + 2048 + 8192) {
            D21b[id - 18432] = bf16_rn(D21[id - 18432]);
        }
        return;
    }

    __shared__ float stl[64 * 33];  // St (64x32), padded
    __shared__ float colbuf[32];    // this block's C2/D21 column
    __shared__ float s1[64];

    const int r = blk;   // 0..383
    const int c = t;     // 0..63
#pragma unroll
    for (int j = 0; j < 32; j++) {
        const int id = j * 64 + t;
        stl[(id >> 5) * 33 + (id & 31)] = St[id];
    }
    if (t < 32)
        colbuf[t] = (r < 64) ? C2[t * 64 + r]
                  : (r < 320 ? D21[t * 256 + (r - 64)] : 0.f);
    __syncthreads();

    float v1;
    if (r < 64) {
        float s = 0.f;
#pragma unroll
        for (int p = 0; p < 32; p++) s += stl[c * 33 + p] * colbuf[p];
        v1 = s;
    } else if (r < 320) {
        float s = 0.f;
#pragma unroll
        for (int p = 0; p < 32; p++) s += stl[c * 33 + p] * colbuf[p];
        v1 = s - D12[(r - 64) * 64 + c];
    } else {
        v1 = B2[(r - 320) * 64 + c];
    }
    s1[c] = v1;
    lT1[r * 64 + c] = v1;
    if (c < 32) {
        const float v2 = (r < 320) ? colbuf[c] : 0.f;
        lT2[r * 32 + c] = v2;
    }
    __syncthreads();

    float a = 0.f;
#pragma unroll
    for (int k = 0; k < 64; k++) a += s1[k] * Rinv[k * 64 + c];
    t1[r * 64 + c] = a;

    if (c < 32) {
        float bq = 0.f;
#pragma unroll
        for (int k = 0; k < 32; k++) bq += colbuf[k] * Q[k * 32 + c];
        t2[r * 32 + c] = bq;
    }
}

// ---------------------------------------------------------------------------
// Prep 2: (unchanged)
// ---------------------------------------------------------------------------
__global__ __launch_bounds__(320) void ren_prep2(
    const float* __restrict__ X,
    const float* __restrict__ lT1, const float* __restrict__ t1,
    const float* __restrict__ lT2, const float* __restrict__ t2,
    unsigned short* __restrict__ Wvb, unsigned short* __restrict__ Drowsb,
    float* __restrict__ Dpair, float* __restrict__ lamg)
{
    __shared__ float xcol[384];
    const int c = threadIdx.x;     // 0..319
    const int i = blockIdx.x;      // 0..255 -> H row 64+i
    for (int t = c; t < 384; t += 320) xcol[t] = X[t * 384 + 64 + i];
    __syncthreads();

    float f0 = 0.f, f1 = 0.f, f2 = 0.f, f3 = 0.f;
    float ac[8], au[8], bc8[8], bu[8];
#pragma unroll
    for (int kk = 0; kk < 8; kk++) { ac[kk] = X[kk * 384 + c]; au[kk] = xcol[kk]; }
    for (int k0 = 0; k0 < 384; k0 += 16) {
#pragma unroll
        for (int kk = 0; kk < 8; kk++) {
            bc8[kk] = X[(k0 + 8 + kk) * 384 + c]; bu[kk] = xcol[k0 + 8 + kk];
        }
        f0 += au[0] * ac[0]; f1 += au[1] * ac[1];
        f2 += au[2] * ac[2]; f3 += au[3] * ac[3];
        f0 += au[4] * ac[4]; f1 += au[5] * ac[5];
        f2 += au[6] * ac[6]; f3 += au[7] * ac[7];
        if (k0 + 16 < 384) {
#pragma unroll
            for (int kk = 0; kk < 8; kk++) {
                ac[kk] = X[(k0 + 16 + kk) * 384 + c]; au[kk] = xcol[k0 + 16 + kk];
            }
        }
        f0 += bu[0] * bc8[0]; f1 += bu[1] * bc8[1];
        f2 += bu[2] * bc8[2]; f3 += bu[3] * bc8[3];
        f0 += bu[4] * bc8[4]; f1 += bu[5] * bc8[5];
        f2 += bu[6] * bc8[6]; f3 += bu[7] * bc8[7];
    }

    const float* __restrict__ t1r = t1 + (64 + i) * 64;
    const float* __restrict__ l1r = lT1 + c * 64;
#pragma unroll
    for (int m4 = 0; m4 < 16; m4++) {
        const float4 lv = *(const float4*)(l1r + m4 * 4);
        f0 += t1r[m4 * 4 + 0] * lv.x; f1 += t1r[m4 * 4 + 1] * lv.y;
        f2 += t1r[m4 * 4 + 2] * lv.z; f3 += t1r[m4 * 4 + 3] * lv.w;
    }
    const float* __restrict__ t2r = t2 + (64 + i) * 32;
    const float* __restrict__ l2r = lT2 + c * 32;
#pragma unroll
    for (int m4 = 0; m4 < 8; m4++) {
        const float4 lv = *(const float4*)(l2r + m4 * 4);
        f0 -= t2r[m4 * 4 + 0] * lv.x; f1 -= t2r[m4 * 4 + 1] * lv.y;
        f2 -= t2r[m4 * 4 + 2] * lv.z; f3 -= t2r[m4 * 4 + 3] * lv.w;
    }
    float acc = (f0 + f1) + (f2 + f3) + (((64 + i) == c) ? 0.001f : 0.f);

    if (c < 64) {
        Wvb[i * 128 + c] = bf16_rn(-acc);       // C_1 = -H_21
    } else {
        const int cb = c - 64;
        if (cb == i) lamg[i] = 5.7707801635558536f / acc;  // (2*log2e)*2/H22ii
        if (i < 255) {
            const float dv = (cb <= i - 1) ? -acc : 0.f;
            Drowsb[(i + 1) * 256 + cb] = bf16_rn(dv);
            const int row = i + 1;
            if ((row >> 4) == (cb >> 4)) {      // diagonal 16-block, pair layout
                const int q = row & 15, p = cb & 15;
                Dpair[(row >> 4) * 256 + (q >> 1) * 32 + p * 2 + (q & 1)] = dv;
            }
        } else {
            Drowsb[cb] = 0;
        }
    }
}

// ---------------------------------------------------------------------------
// Fused two-tile triangle (R15, unchanged): both tiles in one tq loop,
// shared dblk/lam LDS reads, interleaved independent FMA+exp chains.
// ---------------------------------------------------------------------------
__device__ __attribute__((always_inline)) inline void triangle16x2(
    float (&vlA)[16], float (&wlA)[16],
    float (&vlB)[16], float (&wlB)[16],
    const float* __restrict__ dblk, const float* __restrict__ lam)
{
#pragma unroll
    for (int tq = 0; tq < 8; tq++) {
        floatx2 aA, bA, aB, bB;
        aA[0] = vlA[2 * tq]; aA[1] = vlA[2 * tq + 1];
        aB[0] = vlB[2 * tq]; aB[1] = vlB[2 * tq + 1];
        bA[0] = 0.f; bA[1] = 0.f;
        bB[0] = 0.f; bB[1] = 0.f;
#pragma unroll
        for (int p4 = 0; p4 < tq; p4++) {
            const float4 d4 = *(const float4*)&dblk[tq * 32 + p4 * 4];  // LDS, shared
            floatx2 de; de[0] = d4.x; de[1] = d4.y;
            floatx2 dz; dz[0] = d4.z; dz[1] = d4.w;
            aA += de * wlA[2 * p4];  bA += dz * wlA[2 * p4 + 1];
            aB += de * wlB[2 * p4];  bB += dz * wlB[2 * p4 + 1];
        }
        aA += bA; aB += bB;
        floatx2 lm2; lm2[0] = lam[2 * tq]; lm2[1] = lam[2 * tq + 1];  // LDS, shared
        aA *= lm2; aB *= lm2;
        const float e0A = __builtin_amdgcn_exp2f(aA[0]);
        const float e1A = __builtin_amdgcn_exp2f(aA[1]);
        const float e0B = __builtin_amdgcn_exp2f(aB[0]);
        const float e1B = __builtin_amdgcn_exp2f(aB[1]);
        wlA[2 * tq]     = 1.f - 2.f * __builtin_amdgcn_rcpf(e0A + 1.f);
        wlA[2 * tq + 1] = 1.f - 2.f * __builtin_amdgcn_rcpf(e1A + 1.f);
        wlB[2 * tq]     = 1.f - 2.f * __builtin_amdgcn_rcpf(e0B + 1.f);
        wlB[2 * tq + 1] = 1.f - 2.f * __builtin_amdgcn_rcpf(e1B + 1.f);
    }
}

// ---------------------------------------------------------------------------
// Main — R18 = R17 resubmitted (R17 never ran: container-acquisition infra
// failure, same signature as R13's attempt). R17 = R15 (two independent
// 16-row tiles per wave, shared operand loads — best passing config, ~33us)
// + DEAD-LOAD ELIMINATION: Drowsb is strictly lower-triangular, so for
// block n+1 the hf[c] fragments with c >= (n+2)>>1 are all-zero rows and
// their wsh chunks are still zero — the "uniform MFMA phase" loaded all 8
// every iter (avg needed: 4.27). Each load is fully exposed at-use
// (~230cyc, regalloc-enforced — proven R10-R16 across 5 pinning
// strategies), so the 3.7 dead loads/iter are ~860cyc/iter of pure waste.
// Phase 5 now runs a runtime-bounded, WAVE-UNIFORM c-loop (n uniform -> no
// divergence) loading hf inline and issuing only the needed MFMAs. Skipped
// MFMAs contributed exactly 0 before -> numerics bit-identical.
// ---------------------------------------------------------------------------
__global__ __launch_bounds__(64, 1) void ren_main(
    const float* __restrict__ u, const float* __restrict__ x0,
    const float* __restrict__ b,
    const unsigned short* __restrict__ Wvb,
    const unsigned short* __restrict__ Drowsb,
    const float* __restrict__ Dpair,
    const float* __restrict__ lamg,
    const unsigned short* __restrict__ C2b,
    const unsigned short* __restrict__ D21b,
    float* __restrict__ out)
{
    __shared__ float bufA[16][20];  // tile A acc transpose (stride 20)
    __shared__ float bufB[16][20];  // tile B acc transpose
    __shared__ float dblk[256];     // pair-interleaved 16x16 D tile (shared)
    __shared__ float lamsh[256];
    __shared__ float bsh[256];
    __shared__ short8 wshA[8 * 64]; // tile A w A-frags
    __shared__ short8 wshB[8 * 64]; // tile B w A-frags

    const int L = threadIdx.x;
    const int col = L & 15;
    const int quad = L >> 4;
    const int row0 = blockIdx.x * 32;

#pragma unroll
    for (int j = 0; j < 4; j++) {
        lamsh[j * 64 + L] = lamg[j * 64 + L];
        bsh[j * 64 + L]   = b[64 + j * 64 + L];
    }
    const short8 zero8 = {0, 0, 0, 0, 0, 0, 0, 0};
#pragma unroll
    for (int c = 0; c < 8; c++) { wshA[c * 64 + L] = zero8; wshB[c * 64 + L] = zero8; }

    // z A-frags for both tiles: 4 K-chunks of 32 over [x0 | u]
    short8 zfA[4], zfB[4];
#pragma unroll
    for (int c = 0; c < 4; c++) {
        const float* base = (c < 2 ? x0 : u);
        const float* pA = base + (long)(row0 + col) * 64 + (c & 1) * 32 + quad * 8;
        const float* pB = base + (long)(row0 + 16 + col) * 64 + (c & 1) * 32 + quad * 8;
        zfA[c] = pack8v(*(const float4*)pA, *(const float4*)(pA + 4));
        zfB[c] = pack8v(*(const float4*)pB, *(const float4*)(pB + 4));
    }

    // ---- prologue: acc for block 0 (v-GEMM only), shared operands ----
    float4 dcur = *(const float4*)(Dpair + 4 * L);
    floatx4 accA0 = {0.f, 0.f, 0.f, 0.f}, accA1 = {0.f, 0.f, 0.f, 0.f};
    floatx4 accB0 = {0.f, 0.f, 0.f, 0.f}, accB1 = {0.f, 0.f, 0.f, 0.f};
    {
        short8 v0 = *(const short8*)(Wvb + col * 128 + quad * 8);
        short8 v1 = *(const short8*)(Wvb + col * 128 + 32 + quad * 8);
        short8 v2 = *(const short8*)(Wvb + col * 128 + 64 + quad * 8);
        short8 v3 = *(const short8*)(Wvb + col * 128 + 96 + quad * 8);
        accA0 = MFMA16(zfA[0], v0, accA0, 0, 0, 0);
        accB0 = MFMA16(zfB[0], v0, accB0, 0, 0, 0);
        accA1 = MFMA16(zfA[1], v1, accA1, 0, 0, 0);
        accB1 = MFMA16(zfB[1], v1, accB1, 0, 0, 0);
        accA0 = MFMA16(zfA[2], v2, accA0, 0, 0, 0);
        accB0 = MFMA16(zfB[2], v2, accB0, 0, 0, 0);
        accA1 = MFMA16(zfA[3], v3, accA1, 0, 0, 0);
        accB1 = MFMA16(zfB[3], v3, accB1, 0, 0, 0);
    }

#pragma unroll 1   // keep the loop rolled (I$-resident hot body)
    for (int n = 0; n < 15; n++) {
        // ---- (1) prefetch block-(n+1) v-GEMM operands (shared) ----
        const int rb = 16 * (n + 1) + col;
        float4 dnxt = *(const float4*)(Dpair + (n + 1) * 256 + 4 * L);
        short8 vf[4];
#pragma unroll
        for (int c = 0; c < 4; c++)
            vf[c] = *(const short8*)(Wvb + rb * 128 + c * 32 + quad * 8);

        // ---- (2) stage current D tile; transpose both tiles via LDS ----
        *(float4*)&dblk[4 * L] = dcur;
        const float bwv = bsh[16 * n + col];
#pragma unroll
        for (int r = 0; r < 4; r++) {
            bufA[quad * 4 + r][col] = accA0[r] + accA1[r] + bwv;
            bufB[quad * 4 + r][col] = accB0[r] + accB1[r] + bwv;
        }

        float vlA[16], wlA[16], vlB[16], wlB[16];
#pragma unroll
        for (int p4 = 0; p4 < 4; p4++) {
            const float4 ta = *(const float4*)&bufA[col][p4 * 4];  // LDS read
            const float4 tb = *(const float4*)&bufB[col][p4 * 4];
            vlA[p4 * 4 + 0] = ta.x; vlA[p4 * 4 + 1] = ta.y;
            vlA[p4 * 4 + 2] = ta.z; vlA[p4 * 4 + 3] = ta.w;
            vlB[p4 * 4 + 0] = tb.x; vlB[p4 * 4 + 1] = tb.y;
            vlB[p4 * 4 + 2] = tb.z; vlB[p4 * 4 + 3] = tb.w;
        }

        // ---- (3) fused two-tile triangle (chains interleaved) ----
        triangle16x2(vlA, wlA, vlB, wlB, dblk, &lamsh[16 * n]);

        // ---- (4) fold w blocks into wsh chunks (half per parity) ----
        {
            float4 waA, wbA, waB, wbB;
            if (quad & 1) {
                waA = make_float4(wlA[8], wlA[9], wlA[10], wlA[11]);
                wbA = make_float4(wlA[12], wlA[13], wlA[14], wlA[15]);
                waB = make_float4(wlB[8], wlB[9], wlB[10], wlB[11]);
                wbB = make_float4(wlB[12], wlB[13], wlB[14], wlB[15]);
            } else {
                waA = make_float4(wlA[0], wlA[1], wlA[2], wlA[3]);
                wbA = make_float4(wlA[4], wlA[5], wlA[6], wlA[7]);
                waB = make_float4(wlB[0], wlB[1], wlB[2], wlB[3]);
                wbB = make_float4(wlB[4], wlB[5], wlB[6], wlB[7]);
            }
            const short8 nfA = pack8v(waA, wbA);
            const short8 nfB = pack8v(waB, wbB);
            if ((quad >> 1) == (n & 1)) {
                wshA[(n >> 1) * 64 + L] = nfA;
                wshB[(n >> 1) * 64 + L] = nfB;
            }
        }

        // ---- (5) MFMA phase for block n+1: v-GEMM always; w-GEMM only for
        //          the non-zero triangular chunks c < (n+2)>>1 (uniform) ----
        floatx4 aA0 = {0.f, 0.f, 0.f, 0.f}, aA1 = {0.f, 0.f, 0.f, 0.f};
        floatx4 aB0 = {0.f, 0.f, 0.f, 0.f}, aB1 = {0.f, 0.f, 0.f, 0.f};
        aA0 = MFMA16(zfA[0], vf[0], aA0, 0, 0, 0);
        aB0 = MFMA16(zfB[0], vf[0], aB0, 0, 0, 0);
        aA1 = MFMA16(zfA[1], vf[1], aA1, 0, 0, 0);
        aB1 = MFMA16(zfB[1], vf[1], aB1, 0, 0, 0);
        aA0 = MFMA16(zfA[2], vf[2], aA0, 0, 0, 0);
        aB0 = MFMA16(zfB[2], vf[2], aB0, 0, 0, 0);
        aA1 = MFMA16(zfA[3], vf[3], aA1, 0, 0, 0);
        aB1 = MFMA16(zfB[3], vf[3], aB1, 0, 0, 0);
        const int lim = (n + 2) >> 1;   // wave-uniform bound: chunks 0..n>>1
#pragma unroll 1
        for (int c = 0; c < lim; c++) {
            const short8 h = *(const short8*)(Drowsb + rb * 256 + c * 32 + quad * 8);
            const short8 wA = wshA[c * 64 + L];
            const short8 wB = wshB[c * 64 + L];
            if (c & 1) {
                aA1 = MFMA16(wA, h, aA1, 0, 0, 0);
                aB1 = MFMA16(wB, h, aB1, 0, 0, 0);
            } else {
                aA0 = MFMA16(wA, h, aA0, 0, 0, 0);
                aB0 = MFMA16(wB, h, aB0, 0, 0, 0);
            }
        }
        accA0 = aA0; accA1 = aA1; accB0 = aB0; accB1 = aB1;
        dcur = dnxt;
    }

    // ---- peeled n = 15: triangles only (no next block) ----
    {
        *(float4*)&dblk[4 * L] = dcur;
        const float bwv = bsh[240 + col];
#pragma unroll
        for (int r = 0; r < 4; r++) {
            bufA[quad * 4 + r][col] = accA0[r] + accA1[r] + bwv;
            bufB[quad * 4 + r][col] = accB0[r] + accB1[r] + bwv;
        }

        float vlA[16], wlA[16], vlB[16], wlB[16];
#pragma unroll
        for (int p4 = 0; p4 < 4; p4++) {
            const float4 ta = *(const float4*)&bufA[col][p4 * 4];
            const float4 tb = *(const float4*)&bufB[col][p4 * 4];
            vlA[p4 * 4 + 0] = ta.x; vlA[p4 * 4 + 1] = ta.y;
            vlA[p4 * 4 + 2] = ta.z; vlA[p4 * 4 + 3] = ta.w;
            vlB[p4 * 4 + 0] = tb.x; vlB[p4 * 4 + 1] = tb.y;
            vlB[p4 * 4 + 2] = tb.z; vlB[p4 * 4 + 3] = tb.w;
        }

        triangle16x2(vlA, wlA, vlB, wlB, dblk, &lamsh[240]);

        float4 waA, wbA, waB, wbB;
        if (quad & 1) {
            waA = make_float4(wlA[8], wlA[9], wlA[10], wlA[11]);
            wbA = make_float4(wlA[12], wlA[13], wlA[14], wlA[15]);
            waB = make_float4(wlB[8], wlB[9], wlB[10], wlB[11]);
            wbB = make_float4(wlB[12], wlB[13], wlB[14], wlB[15]);
        } else {
            waA = make_float4(wlA[0], wlA[1], wlA[2], wlA[3]);
            wbA = make_float4(wlA[4], wlA[5], wlA[6], wlA[7]);
            waB = make_float4(wlB[0], wlB[1], wlB[2], wlB[3]);
            wbB = make_float4(wlB[4], wlB[5], wlB[6], wlB[7]);
        }
        const short8 nfA = pack8v(waA, wbA);
        const short8 nfB = pack8v(waB, wbB);
        if (quad >= 2) {                  // n=15 odd -> quads 2,3
            wshA[7 * 64 + L] = nfA;
            wshB[7 * 64 + L] = nfB;
        }
    }

    // ---- y phase: Y[16][32] per tile, shared B-operands ----
    floatx4 yA0 = {0.f, 0.f, 0.f, 0.f}, yA1 = {0.f, 0.f, 0.f, 0.f};
    floatx4 yB0 = {0.f, 0.f, 0.f, 0.f}, yB1 = {0.f, 0.f, 0.f, 0.f};
    {
        const short8 yc0 = *(const short8*)(C2b + col * 64 + quad * 8);
        const short8 yc1 = *(const short8*)(C2b + col * 64 + 32 + quad * 8);
        const short8 yc2 = *(const short8*)(C2b + (16 + col) * 64 + quad * 8);
        const short8 yc3 = *(const short8*)(C2b + (16 + col) * 64 + 32 + quad * 8);
        yA0 = MFMA16(zfA[0], yc0, yA0, 0, 0, 0);
        yB0 = MFMA16(zfB[0], yc0, yB0, 0, 0, 0);
        yA1 = MFMA16(zfA[0], yc2, yA1, 0, 0, 0);
        yB1 = MFMA16(zfB[0], yc2, yB1, 0, 0, 0);
        yA0 = MFMA16(zfA[1], yc1, yA0, 0, 0, 0);
        yB0 = MFMA16(zfB[1], yc1, yB0, 0, 0, 0);
        yA1 = MFMA16(zfA[1], yc3, yA1, 0, 0, 0);
        yB1 = MFMA16(zfB[1], yc3, yB1, 0, 0, 0);
    }
#pragma unroll
    for (int c = 0; c < 8; c++) {
        const short8 wA = wshA[c * 64 + L];
        const short8 wB = wshB[c * 64 + L];
        const short8 b0 = *(const short8*)(D21b + col * 256 + c * 32 + quad * 8);
        const short8 b1 = *(const short8*)(D21b + (16 + col) * 256 + c * 32 + quad * 8);
        yA0 = MFMA16(wA, b0, yA0, 0, 0, 0);
        yB0 = MFMA16(wB, b0, yB0, 0, 0, 0);
        yA1 = MFMA16(wA, b1, yA1, 0, 0, 0);
        yB1 = MFMA16(wB, b1, yB1, 0, 0, 0);
    }
    const float by0 = b[320 + col];
    const float by1 = b[336 + col];
#pragma unroll
    for (int r = 0; r < 4; r++) {
        out[(long)(row0 + quad * 4 + r) * 32 + col]           = yA0[r] + by0;
        out[(long)(row0 + quad * 4 + r) * 32 + 16 + col]      = yA1[r] + by1;
        out[(long)(row0 + 16 + quad * 4 + r) * 32 + col]      = yB0[r] + by0;
        out[(long)(row0 + 16 + quad * 4 + r) * 32 + 16 + col] = yB1[r] + by1;
    }
}

// ---------------------------------------------------------------------------
extern "C" void kernel_launch(void* const* d_in, const int* in_sizes, int n_in,
                              void* d_out, int out_size, void* d_ws, size_t ws_size,
                              hipStream_t stream)
{
    const float* u    = (const float*)d_in[0];
    const float* x0   = (const float*)d_in[1];
    const float* B2   = (const float*)d_in[2];
    const float* C2   = (const float*)d_in[3];
    const float* D12  = (const float*)d_in[4];
    const float* D21  = (const float*)d_in[5];
    const float* b    = (const float*)d_in[6];
    const float* X    = (const float*)d_in[7];
    // d_in[8] = Y1 (unused in forward)
    const float* St   = (const float*)d_in[9];
    const float* Q    = (const float*)d_in[10];
    const float* Rinv = (const float*)d_in[11];
    float* out = (float*)d_out;

    float* ws     = (float*)d_ws;
    float* lT1    = ws;                 // 384*64
    float* t1     = lT1 + 384 * 64;     // 384*64
    float* lT2    = t1 + 384 * 64;      // 384*32
    float* t2     = lT2 + 384 * 32;     // 384*32
    float* lamg   = t2 + 384 * 32;      // 256
    float* Dpair  = lamg + 256;         // 16*256 fp32 (pair-interleaved)
    unsigned short* Drowsb = (unsigned short*)(Dpair + 16 * 256); // 256*256
    unsigned short* Wvb    = Drowsb + 256 * 256;                  // 256*128
    unsigned short* C2b    = Wvb + 256 * 128;                     // 32*64
    unsigned short* D21b   = C2b + 32 * 64;                       // 32*256

    ren_prep13<<<dim3(800), dim3(64), 0, stream>>>(B2, C2, D12, D21, St, Q, Rinv,
                                                   lT1, t1, lT2, t2, Wvb, C2b, D21b);
    ren_prep2<<<dim3(256), dim3(320), 0, stream>>>(X, lT1, t1, lT2, t2,
                                                   Wvb, Drowsb, Dpair, lamg);

    const int batch = in_sizes[0] / 64;            // 32768
    ren_main<<<dim3(batch / 32), dim3(64), 0, stream>>>(u, x0, b, Wvb, Drowsb,
                                                        Dpair, lamg, C2b, D21b, out);
}

// Round 12
// 126.057 us; speedup vs baseline: 1.0920x; 1.0920x over previous
//
#include <hip/hip_runtime.h>
#include <hip/hip_bf16.h>

// REN forward: BATCH=32768, N_X=64, N_UNITS=256, N_Y=32, N_U=64
typedef __attribute__((ext_vector_type(8))) short short8;
typedef __attribute__((ext_vector_type(4))) float floatx4;
typedef __attribute__((ext_vector_type(2))) float floatx2;

#define MFMA16 __builtin_amdgcn_mfma_f32_16x16x32_bf16

__device__ inline unsigned short bf16_rn(float f) {
    return (unsigned short)((__float_as_uint(f) + 0x8000u) >> 16);
}
// Packed f32->bf16 (RNE), value-based: no address-taken private arrays.
__device__ __attribute__((always_inline)) inline short8 pack8v(float4 a, float4 b) {
    union { short8 s; unsigned int u[4]; } r;
    union { __hip_bfloat162 h; unsigned int u; } c;
    c.h = __float22bfloat162_rn(make_float2(a.x, a.y)); r.u[0] = c.u;
    c.h = __float22bfloat162_rn(make_float2(a.z, a.w)); r.u[1] = c.u;
    c.h = __float22bfloat162_rn(make_float2(b.x, b.y)); r.u[2] = c.u;
    c.h = __float22bfloat162_rn(make_float2(b.z, b.w)); r.u[3] = c.u;
    return r.s;
}

// ---------------------------------------------------------------------------
// Prep13: (unchanged)
// ---------------------------------------------------------------------------
__global__ __launch_bounds__(64) void ren_prep13(
    const float* __restrict__ B2, const float* __restrict__ C2,
    const float* __restrict__ D12, const float* __restrict__ D21,
    const float* __restrict__ St, const float* __restrict__ Q,
    const float* __restrict__ Rinv,
    float* __restrict__ lT1, float* __restrict__ t1,
    float* __restrict__ lT2, float* __restrict__ t2,
    unsigned short* __restrict__ Wvb, unsigned short* __restrict__ C2b,
    unsigned short* __restrict__ D21b)
{
    const int t = threadIdx.x;
    const int blk = blockIdx.x;
    if (blk >= 384) {   // bf16-copy role (uniform branch)
        const int id = (blk - 384) * 64 + t;
        if (id < 16384) {
            Wvb[(id >> 6) * 128 + 64 + (id & 63)] = bf16_rn(D12[id]);
        } else if (id < 16384 + 2048) {
            C2b[id - 16384] = bf16_rn(C2[id - 16384]);
        } else if (id < 16384 + 2048 + 8192) {
            D21b[id - 18432] = bf16_rn(D21[id - 18432]);
        }
        return;
    }

    __shared__ float stl[64 * 33];  // St (64x32), padded
    __shared__ float colbuf[32];    // this block's C2/D21 column
    __shared__ float s1[64];

    const int r = blk;   // 0..383
    const int c = t;     // 0..63
#pragma unroll
    for (int j = 0; j < 32; j++) {
        const int id = j * 64 + t;
        stl[(id >> 5) * 33 + (id & 31)] = St[id];
    }
    if (t < 32)
        colbuf[t] = (r < 64) ? C2[t * 64 + r]
                  : (r < 320 ? D21[t * 256 + (r - 64)] : 0.f);
    __syncthreads();

    float v1;
    if (r < 64) {
        float s = 0.f;
#pragma unroll
        for (int p = 0; p < 32; p++) s += stl[c * 33 + p] * colbuf[p];
        v1 = s;
    } else if (r < 320) {
        float s = 0.f;
#pragma unroll
        for (int p = 0; p < 32; p++) s += stl[c * 33 + p] * colbuf[p];
        v1 = s - D12[(r - 64) * 64 + c];
    } else {
        v1 = B2[(r - 320) * 64 + c];
    }
    s1[c] = v1;
    lT1[r * 64 + c] = v1;
    if (c < 32) {
        const float v2 = (r < 320) ? colbuf[c] : 0.f;
        lT2[r * 32 + c] = v2;
    }
    __syncthreads();

    float a = 0.f;
#pragma unroll
    for (int k = 0; k < 64; k++) a += s1[k] * Rinv[k * 64 + c];
    t1[r * 64 + c] = a;

    if (c < 32) {
        float bq = 0.f;
#pragma unroll
        for (int k = 0; k < 32; k++) bq += colbuf[k] * Q[k * 32 + c];
        t2[r * 32 + c] = bq;
    }
}

// ---------------------------------------------------------------------------
// Prep 2: (unchanged)
// ---------------------------------------------------------------------------
__global__ __launch_bounds__(320) void ren_prep2(
    const float* __restrict__ X,
    const float* __restrict__ lT1, const float* __restrict__ t1,
    const float* __restrict__ lT2, const float* __restrict__ t2,
    unsigned short* __restrict__ Wvb, unsigned short* __restrict__ Drowsb,
    float* __restrict__ Dpair, float* __restrict__ lamg)
{
    __shared__ float xcol[384];
    const int c = threadIdx.x;     // 0..319
    const int i = blockIdx.x;      // 0..255 -> H row 64+i
    for (int t = c; t < 384; t += 320) xcol[t] = X[t * 384 + 64 + i];
    __syncthreads();

    float f0 = 0.f, f1 = 0.f, f2 = 0.f, f3 = 0.f;
    float ac[8], au[8], bc8[8], bu[8];
#pragma unroll
    for (int kk = 0; kk < 8; kk++) { ac[kk] = X[kk * 384 + c]; au[kk] = xcol[kk]; }
    for (int k0 = 0; k0 < 384; k0 += 16) {
#pragma unroll
        for (int kk = 0; kk < 8; kk++) {
            bc8[kk] = X[(k0 + 8 + kk) * 384 + c]; bu[kk] = xcol[k0 + 8 + kk];
        }
        f0 += au[0] * ac[0]; f1 += au[1] * ac[1];
        f2 += au[2] * ac[2]; f3 += au[3] * ac[3];
        f0 += au[4] * ac[4]; f1 += au[5] * ac[5];
        f2 += au[6] * ac[6]; f3 += au[7] * ac[7];
        if (k0 + 16 < 384) {
#pragma unroll
            for (int kk = 0; kk < 8; kk++) {
                ac[kk] = X[(k0 + 16 + kk) * 384 + c]; au[kk] = xcol[k0 + 16 + kk];
            }
        }
        f0 += bu[0] * bc8[0]; f1 += bu[1] * bc8[1];
        f2 += bu[2] * bc8[2]; f3 += bu[3] * bc8[3];
        f0 += bu[4] * bc8[4]; f1 += bu[5] * bc8[5];
        f2 += bu[6] * bc8[6]; f3 += bu[7] * bc8[7];
    }

    const float* __restrict__ t1r = t1 + (64 + i) * 64;
    const float* __restrict__ l1r = lT1 + c * 64;
#pragma unroll
    for (int m4 = 0; m4 < 16; m4++) {
        const float4 lv = *(const float4*)(l1r + m4 * 4);
        f0 += t1r[m4 * 4 + 0] * lv.x; f1 += t1r[m4 * 4 + 1] * lv.y;
        f2 += t1r[m4 * 4 + 2] * lv.z; f3 += t1r[m4 * 4 + 3] * lv.w;
    }
    const float* __restrict__ t2r = t2 + (64 + i) * 32;
    const float* __restrict__ l2r = lT2 + c * 32;
#pragma unroll
    for (int m4 = 0; m4 < 8; m4++) {
        const float4 lv = *(const float4*)(l2r + m4 * 4);
        f0 -= t2r[m4 * 4 + 0] * lv.x; f1 -= t2r[m4 * 4 + 1] * lv.y;
        f2 -= t2r[m4 * 4 + 2] * lv.z; f3 -= t2r[m4 * 4 + 3] * lv.w;
    }
    float acc = (f0 + f1) + (f2 + f3) + (((64 + i) == c) ? 0.001f : 0.f);

    if (c < 64) {
        Wvb[i * 128 + c] = bf16_rn(-acc);       // C_1 = -H_21
    } else {
        const int cb = c - 64;
        if (cb == i) lamg[i] = 5.7707801635558536f / acc;  // (2*log2e)*2/H22ii
        if (i < 255) {
            const float dv = (cb <= i - 1) ? -acc : 0.f;
            Drowsb[(i + 1) * 256 + cb] = bf16_rn(dv);
            const int row = i + 1;
            if ((row >> 4) == (cb >> 4)) {      // diagonal 16-block, pair layout
                const int q = row & 15, p = cb & 15;
                Dpair[(row >> 4) * 256 + (q >> 1) * 32 + p * 2 + (q & 1)] = dv;
            }
        } else {
            Drowsb[cb] = 0;
        }
    }
}

// ---------------------------------------------------------------------------
// Fused two-tile triangle (R15, unchanged): both tiles in one tq loop,
// shared dblk/lam LDS reads, interleaved independent FMA+exp chains.
// ---------------------------------------------------------------------------
__device__ __attribute__((always_inline)) inline void triangle16x2(
    float (&vlA)[16], float (&wlA)[16],
    float (&vlB)[16], float (&wlB)[16],
    const float* __restrict__ dblk, const float* __restrict__ lam)
{
#pragma unroll
    for (int tq = 0; tq < 8; tq++) {
        floatx2 aA, bA, aB, bB;
        aA[0] = vlA[2 * tq]; aA[1] = vlA[2 * tq + 1];
        aB[0] = vlB[2 * tq]; aB[1] = vlB[2 * tq + 1];
        bA[0] = 0.f; bA[1] = 0.f;
        bB[0] = 0.f; bB[1] = 0.f;
#pragma unroll
        for (int p4 = 0; p4 < tq; p4++) {
            const float4 d4 = *(const float4*)&dblk[tq * 32 + p4 * 4];  // LDS, shared
            floatx2 de; de[0] = d4.x; de[1] = d4.y;
            floatx2 dz; dz[0] = d4.z; dz[1] = d4.w;
            aA += de * wlA[2 * p4];  bA += dz * wlA[2 * p4 + 1];
            aB += de * wlB[2 * p4];  bB += dz * wlB[2 * p4 + 1];
        }
        aA += bA; aB += bB;
        floatx2 lm2; lm2[0] = lam[2 * tq]; lm2[1] = lam[2 * tq + 1];  // LDS, shared
        aA *= lm2; aB *= lm2;
        const float e0A = __builtin_amdgcn_exp2f(aA[0]);
        const float e1A = __builtin_amdgcn_exp2f(aA[1]);
        const float e0B = __builtin_amdgcn_exp2f(aB[0]);
        const float e1B = __builtin_amdgcn_exp2f(aB[1]);
        wlA[2 * tq]     = 1.f - 2.f * __builtin_amdgcn_rcpf(e0A + 1.f);
        wlA[2 * tq + 1] = 1.f - 2.f * __builtin_amdgcn_rcpf(e1A + 1.f);
        wlB[2 * tq]     = 1.f - 2.f * __builtin_amdgcn_rcpf(e0B + 1.f);
        wlB[2 * tq + 1] = 1.f - 2.f * __builtin_amdgcn_rcpf(e1B + 1.f);
    }
}

// One pipeline iteration for block nI (consumes CUR = ops(nI+1), loaded one
// iteration earlier; issues loads for NXT = ops(nI+2)). Macro so every
// register-set reference is a static name (rule-#20-safe).
#define REN_ITER(n_, VC, HC, VN, HN, DO_LOAD_)                                 \
  {                                                                            \
    const int nI = (n_);                                                       \
    if (DO_LOAD_) {                                                            \
      const int rb2 = 16 * (nI + 2) + col;                                     \
      _Pragma("unroll") for (int cc = 0; cc < 4; cc++)                         \
        VN[cc] = *(const short8*)(Wvb + rb2 * 128 + cc * 32 + quad * 8);       \
      _Pragma("unroll") for (int cc = 0; cc < 8; cc++)                         \
        HN[cc] = *(const short8*)(Drowsb + rb2 * 256 + cc * 32 + quad * 8);    \
    }                                                                          \
    const float4 dnxtI = *(const float4*)(Dpair + (nI + 1) * 256 + 4 * L);     \
    *(float4*)&dblk[4 * L] = dcur;                                             \
    const float bwvI = bsh[16 * nI + col];                                     \
    _Pragma("unroll") for (int r = 0; r < 4; r++) {                            \
      bufA[quad * 4 + r][col] = accA0[r] + accA1[r] + bwvI;                    \
      bufB[quad * 4 + r][col] = accB0[r] + accB1[r] + bwvI;                    \
    }                                                                          \
    float vlA[16], wlA[16], vlB[16], wlB[16];                                  \
    _Pragma("unroll") for (int p4 = 0; p4 < 4; p4++) {                         \
      const float4 ta = *(const float4*)&bufA[col][p4 * 4];                    \
      const float4 tb = *(const float4*)&bufB[col][p4 * 4];                    \
      vlA[p4 * 4 + 0] = ta.x; vlA[p4 * 4 + 1] = ta.y;                          \
      vlA[p4 * 4 + 2] = ta.z; vlA[p4 * 4 + 3] = ta.w;                          \
      vlB[p4 * 4 + 0] = tb.x; vlB[p4 * 4 + 1] = tb.y;                          \
      vlB[p4 * 4 + 2] = tb.z; vlB[p4 * 4 + 3] = tb.w;                          \
    }                                                                          \
    triangle16x2(vlA, wlA, vlB, wlB, dblk, &lamsh[16 * nI]);                   \
    {                                                                          \
      float4 waA, wbA, waB, wbB;                                               \
      if (quad & 1) {                                                          \
        waA = make_float4(wlA[8], wlA[9], wlA[10], wlA[11]);                   \
        wbA = make_float4(wlA[12], wlA[13], wlA[14], wlA[15]);                 \
        waB = make_float4(wlB[8], wlB[9], wlB[10], wlB[11]);                   \
        wbB = make_float4(wlB[12], wlB[13], wlB[14], wlB[15]);                 \
      } else {                                                                 \
        waA = make_float4(wlA[0], wlA[1], wlA[2], wlA[3]);                     \
        wbA = make_float4(wlA[4], wlA[5], wlA[6], wlA[7]);                     \
        waB = make_float4(wlB[0], wlB[1], wlB[2], wlB[3]);                     \
        wbB = make_float4(wlB[4], wlB[5], wlB[6], wlB[7]);                     \
      }                                                                        \
      const short8 nfA = pack8v(waA, wbA);                                     \
      const short8 nfB = pack8v(waB, wbB);                                     \
      if ((quad >> 1) == (nI & 1)) {                                           \
        wshA[(nI >> 1) * 64 + L] = nfA;                                        \
        wshB[(nI >> 1) * 64 + L] = nfB;                                        \
      }                                                                        \
    }                                                                          \
    floatx4 aA0 = {0.f, 0.f, 0.f, 0.f}, aA1 = {0.f, 0.f, 0.f, 0.f};            \
    floatx4 aB0 = {0.f, 0.f, 0.f, 0.f}, aB1 = {0.f, 0.f, 0.f, 0.f};            \
    aA0 = MFMA16(zfA[0], VC[0], aA0, 0, 0, 0);                                 \
    aB0 = MFMA16(zfB[0], VC[0], aB0, 0, 0, 0);                                 \
    aA1 = MFMA16(zfA[1], VC[1], aA1, 0, 0, 0);                                 \
    aB1 = MFMA16(zfB[1], VC[1], aB1, 0, 0, 0);                                 \
    aA0 = MFMA16(zfA[2], VC[2], aA0, 0, 0, 0);                                 \
    aB0 = MFMA16(zfB[2], VC[2], aB0, 0, 0, 0);                                 \
    aA1 = MFMA16(zfA[3], VC[3], aA1, 0, 0, 0);                                 \
    aB1 = MFMA16(zfB[3], VC[3], aB1, 0, 0, 0);                                 \
    _Pragma("unroll") for (int cc = 0; cc < 8; cc++) {                         \
      const short8 wA = wshA[cc * 64 + L];                                     \
      const short8 wB = wshB[cc * 64 + L];                                     \
      if (cc & 1) {                                                            \
        aA1 = MFMA16(wA, HC[cc], aA1, 0, 0, 0);                                \
        aB1 = MFMA16(wB, HC[cc], aB1, 0, 0, 0);                                \
      } else {                                                                 \
        aA0 = MFMA16(wA, HC[cc], aA0, 0, 0, 0);                                \
        aB0 = MFMA16(wB, HC[cc], aB0, 0, 0, 0);                                \
      }                                                                        \
    }                                                                          \
    accA0 = aA0; accA1 = aA1; accB0 = aB0; accB1 = aB1;                        \
    dcur = dnxtI;                                                              \
  }

// ---------------------------------------------------------------------------
// Main — R19 = R15 (two 16-row tiles/wave, shared operand loads; best
// passing, ren_main ~44us) + 2-DEEP OPERAND PIPELINE. R18 proved load COUNT
// isn't the cost (FETCH down, time up) — load SCHEDULING is: same-iteration
// prefetch can be legally sunk to its uses. Fix: load ops(n+2) at iter n,
// consume ops(n+1) loaded at iter n-1, via two statically-named register
// sets in a pair-unrolled loop. Odd-body loads' consumers sit across the
// loop back-edge — structurally unsinkable, >= 1 full triangle of slack;
// even-body loads at worst fall back to R15 behavior. Numerics identical.
// ---------------------------------------------------------------------------
__global__ __launch_bounds__(64, 1) void ren_main(
    const float* __restrict__ u, const float* __restrict__ x0,
    const float* __restrict__ b,
    const unsigned short* __restrict__ Wvb,
    const unsigned short* __restrict__ Drowsb,
    const float* __restrict__ Dpair,
    const float* __restrict__ lamg,
    const unsigned short* __restrict__ C2b,
    const unsigned short* __restrict__ D21b,
    float* __restrict__ out)
{
    __shared__ float bufA[16][20];  // tile A acc transpose (stride 20)
    __shared__ float bufB[16][20];  // tile B acc transpose
    __shared__ float dblk[256];     // pair-interleaved 16x16 D tile (shared)
    __shared__ float lamsh[256];
    __shared__ float bsh[256];
    __shared__ short8 wshA[8 * 64]; // tile A w A-frags
    __shared__ short8 wshB[8 * 64]; // tile B w A-frags

    const int L = threadIdx.x;
    const int col = L & 15;
    const int quad = L >> 4;
    const int row0 = blockIdx.x * 32;

#pragma unroll
    for (int j = 0; j < 4; j++) {
        lamsh[j * 64 + L] = lamg[j * 64 + L];
        bsh[j * 64 + L]   = b[64 + j * 64 + L];
    }
    const short8 zero8 = {0, 0, 0, 0, 0, 0, 0, 0};
#pragma unroll
    for (int c = 0; c < 8; c++) { wshA[c * 64 + L] = zero8; wshB[c * 64 + L] = zero8; }

    // z A-frags for both tiles: 4 K-chunks of 32 over [x0 | u]
    short8 zfA[4], zfB[4];
#pragma unroll
    for (int c = 0; c < 4; c++) {
        const float* base = (c < 2 ? x0 : u);
        const float* pA = base + (long)(row0 + col) * 64 + (c & 1) * 32 + quad * 8;
        const float* pB = base + (long)(row0 + 16 + col) * 64 + (c & 1) * 32 + quad * 8;
        zfA[c] = pack8v(*(const float4*)pA, *(const float4*)(pA + 4));
        zfB[c] = pack8v(*(const float4*)pB, *(const float4*)(pB + 4));
    }

    // ---- prologue: acc for block 0 (v-GEMM only), shared operands ----
    float4 dcur = *(const float4*)(Dpair + 4 * L);
    floatx4 accA0 = {0.f, 0.f, 0.f, 0.f}, accA1 = {0.f, 0.f, 0.f, 0.f};
    floatx4 accB0 = {0.f, 0.f, 0.f, 0.f}, accB1 = {0.f, 0.f, 0.f, 0.f};
    {
        short8 v0 = *(const short8*)(Wvb + col * 128 + quad * 8);
        short8 v1 = *(const short8*)(Wvb + col * 128 + 32 + quad * 8);
        short8 v2 = *(const short8*)(Wvb + col * 128 + 64 + quad * 8);
        short8 v3 = *(const short8*)(Wvb + col * 128 + 96 + quad * 8);
        accA0 = MFMA16(zfA[0], v0, accA0, 0, 0, 0);
        accB0 = MFMA16(zfB[0], v0, accB0, 0, 0, 0);
        accA1 = MFMA16(zfA[1], v1, accA1, 0, 0, 0);
        accB1 = MFMA16(zfB[1], v1, accB1, 0, 0, 0);
        accA0 = MFMA16(zfA[2], v2, accA0, 0, 0, 0);
        accB0 = MFMA16(zfB[2], v2, accB0, 0, 0, 0);
        accA1 = MFMA16(zfA[3], v3, accA1, 0, 0, 0);
        accB1 = MFMA16(zfB[3], v3, accB1, 0, 0, 0);
    }

    // ---- pipeline prologue: ops(1) -> set 1 ----
    short8 sv0[4], sh0[8], sv1[4], sh1[8];
    {
        const int rb = 16 + col;
#pragma unroll
        for (int c = 0; c < 4; c++)
            sv1[c] = *(const short8*)(Wvb + rb * 128 + c * 32 + quad * 8);
#pragma unroll
        for (int c = 0; c < 8; c++)
            sh1[c] = *(const short8*)(Drowsb + rb * 256 + c * 32 + quad * 8);
    }

    // ---- main loop: pair-unrolled, 2-deep pipelined (iters 0..13) ----
#pragma unroll 1
    for (int np = 0; np < 7; np++) {
        REN_ITER(2 * np,     sv1, sh1, sv0, sh0, 1)   // even: use S1, load S0
        REN_ITER(2 * np + 1, sv0, sh0, sv1, sh1, 1)   // odd:  use S0, load S1
    }
    // ---- iter 14: consume ops(15) from S1; nothing left to load ----
    REN_ITER(14, sv1, sh1, sv0, sh0, 0)

    // ---- peeled n = 15: triangles only (no next block) ----
    {
        *(float4*)&dblk[4 * L] = dcur;
        const float bwv = bsh[240 + col];
#pragma unroll
        for (int r = 0; r < 4; r++) {
            bufA[quad * 4 + r][col] = accA0[r] + accA1[r] + bwv;
            bufB[quad * 4 + r][col] = accB0[r] + accB1[r] + bwv;
        }

        float vlA[16], wlA[16], vlB[16], wlB[16];
#pragma unroll
        for (int p4 = 0; p4 < 4; p4++) {
            const float4 ta = *(const float4*)&bufA[col][p4 * 4];
            const float4 tb = *(const float4*)&bufB[col][p4 * 4];
            vlA[p4 * 4 + 0] = ta.x; vlA[p4 * 4 + 1] = ta.y;
            vlA[p4 * 4 + 2] = ta.z; vlA[p4 * 4 + 3] = ta.w;
            vlB[p4 * 4 + 0] = tb.x; vlB[p4 * 4 + 1] = tb.y;
            vlB[p4 * 4 + 2] = tb.z; vlB[p4 * 4 + 3] = tb.w;
        }

        triangle16x2(vlA, wlA, vlB, wlB, dblk, &lamsh[240]);

        float4 waA, wbA, waB, wbB;
        if (quad & 1) {
            waA = make_float4(wlA[8], wlA[9], wlA[10], wlA[11]);
            wbA = make_float4(wlA[12], wlA[13], wlA[14], wlA[15]);
            waB = make_float4(wlB[8], wlB[9], wlB[10], wlB[11]);
            wbB = make_float4(wlB[12], wlB[13], wlB[14], wlB[15]);
        } else {
            waA = make_float4(wlA[0], wlA[1], wlA[2], wlA[3]);
            wbA = make_float4(wlA[4], wlA[5], wlA[6], wlA[7]);
            waB = make_float4(wlB[0], wlB[1], wlB[2], wlB[3]);
            wbB = make_float4(wlB[4], wlB[5], wlB[6], wlB[7]);
        }
        const short8 nfA = pack8v(waA, wbA);
        const short8 nfB = pack8v(waB, wbB);
        if (quad >= 2) {                  // n=15 odd -> quads 2,3
            wshA[7 * 64 + L] = nfA;
            wshB[7 * 64 + L] = nfB;
        }
    }

    // ---- y phase: Y[16][32] per tile, shared B-operands ----
    floatx4 yA0 = {0.f, 0.f, 0.f, 0.f}, yA1 = {0.f, 0.f, 0.f, 0.f};
    floatx4 yB0 = {0.f, 0.f, 0.f, 0.f}, yB1 = {0.f, 0.f, 0.f, 0.f};
    {
        const short8 yc0 = *(const short8*)(C2b + col * 64 + quad * 8);
        const short8 yc1 = *(const short8*)(C2b + col * 64 + 32 + quad * 8);
        const short8 yc2 = *(const short8*)(C2b + (16 + col) * 64 + quad * 8);
        const short8 yc3 = *(const short8*)(C2b + (16 + col) * 64 + 32 + quad * 8);
        yA0 = MFMA16(zfA[0], yc0, yA0, 0, 0, 0);
        yB0 = MFMA16(zfB[0], yc0, yB0, 0, 0, 0);
        yA1 = MFMA16(zfA[0], yc2, yA1, 0, 0, 0);
        yB1 = MFMA16(zfB[0], yc2, yB1, 0, 0, 0);
        yA0 = MFMA16(zfA[1], yc1, yA0, 0, 0, 0);
        yB0 = MFMA16(zfB[1], yc1, yB0, 0, 0, 0);
        yA1 = MFMA16(zfA[1], yc3, yA1, 0, 0, 0);
        yB1 = MFMA16(zfB[1], yc3, yB1, 0, 0, 0);
    }
#pragma unroll
    for (int c = 0; c < 8; c++) {
        const short8 wA = wshA[c * 64 + L];
        const short8 wB = wshB[c * 64 + L];
        const short8 b0 = *(const short8*)(D21b + col * 256 + c * 32 + quad * 8);
        const short8 b1 = *(const short8*)(D21b + (16 + col) * 256 + c * 32 + quad * 8);
        yA0 = MFMA16(wA, b0, yA0, 0, 0, 0);
        yB0 = MFMA16(wB, b0, yB0, 0, 0, 0);
        yA1 = MFMA16(wA, b1, yA1, 0, 0, 0);
        yB1 = MFMA16(wB, b1, yB1, 0, 0, 0);
    }
    const float by0 = b[320 + col];
    const float by1 = b[336 + col];
#pragma unroll
    for (int r = 0; r < 4; r++) {
        out[(long)(row0 + quad * 4 + r) * 32 + col]           = yA0[r] + by0;
        out[(long)(row0 + quad * 4 + r) * 32 + 16 + col]      = yA1[r] + by1;
        out[(long)(row0 + 16 + quad * 4 + r) * 32 + col]      = yB0[r] + by0;
        out[(long)(row0 + 16 + quad * 4 + r) * 32 + 16 + col] = yB1[r] + by1;
    }
}

// ---------------------------------------------------------------------------
extern "C" void kernel_launch(void* const* d_in, const int* in_sizes, int n_in,
                              void* d_out, int out_size, void* d_ws, size_t ws_size,
                              hipStream_t stream)
{
    const float* u    = (const float*)d_in[0];
    const float* x0   = (const float*)d_in[1];
    const float* B2   = (const float*)d_in[2];
    const float* C2   = (const float*)d_in[3];
    const float* D12  = (const float*)d_in[4];
    const float* D21  = (const float*)d_in[5];
    const float* b    = (const float*)d_in[6];
    const float* X    = (const float*)d_in[7];
    // d_in[8] = Y1 (unused in forward)
    const float* St   = (const float*)d_in[9];
    const float* Q    = (const float*)d_in[10];
    const float* Rinv = (const float*)d_in[11];
    float* out = (float*)d_out;

    float* ws     = (float*)d_ws;
    float* lT1    = ws;                 // 384*64
    float* t1     = lT1 + 384 * 64;     // 384*64
    float* lT2    = t1 + 384 * 64;      // 384*32
    float* t2     = lT2 + 384 * 32;     // 384*32
    float* lamg   = t2 + 384 * 32;      // 256
    float* Dpair  = lamg + 256;         // 16*256 fp32 (pair-interleaved)
    unsigned short* Drowsb = (unsigned short*)(Dpair + 16 * 256); // 256*256
    unsigned short* Wvb    = Drowsb + 256 * 256;                  // 256*128
    unsigned short* C2b    = Wvb + 256 * 128;                     // 32*64
    unsigned short* D21b   = C2b + 32 * 64;                       // 32*256

    ren_prep13<<<dim3(800), dim3(64), 0, stream>>>(B2, C2, D12, D21, St, Q, Rinv,
                                                   lT1, t1, lT2, t2, Wvb, C2b, D21b);
    ren_prep2<<<dim3(256), dim3(320), 0, stream>>>(X, lT1, t1, lT2, t2,
                                                   Wvb, Drowsb, Dpair, lamg);

    const int batch = in_sizes[0] / 64;            // 32768
    ren_main<<<dim3(batch / 32), dim3(64), 0, stream>>>(u, x0, b, Wvb, Drowsb,
                                                        Dpair, lamg, C2b, D21b, out);
}

// Round 13
// 125.879 us; speedup vs baseline: 1.0935x; 1.0014x over previous
//
#include <hip/hip_runtime.h>
#include <hip/hip_bf16.h>

// REN forward: BATCH=32768, N_X=64, N_UNITS=256, N_Y=32, N_U=64
typedef __attribute__((ext_vector_type(8))) short short8;
typedef __attribute__((ext_vector_type(4))) float floatx4;
typedef __attribute__((ext_vector_type(2))) float floatx2;

#define MFMA16 __builtin_amdgcn_mfma_f32_16x16x32_bf16

__device__ inline unsigned short bf16_rn(float f) {
    return (unsigned short)((__float_as_uint(f) + 0x8000u) >> 16);
}
// Packed f32->bf16 (RNE), value-based: no address-taken private arrays.
__device__ __attribute__((always_inline)) inline short8 pack8v(float4 a, float4 b) {
    union { short8 s; unsigned int u[4]; } r;
    union { __hip_bfloat162 h; unsigned int u; } c;
    c.h = __float22bfloat162_rn(make_float2(a.x, a.y)); r.u[0] = c.u;
    c.h = __float22bfloat162_rn(make_float2(a.z, a.w)); r.u[1] = c.u;
    c.h = __float22bfloat162_rn(make_float2(b.x, b.y)); r.u[2] = c.u;
    c.h = __float22bfloat162_rn(make_float2(b.z, b.w)); r.u[3] = c.u;
    return r.s;
}

// ---------------------------------------------------------------------------
// Prep13: (unchanged)
// ---------------------------------------------------------------------------
__global__ __launch_bounds__(64) void ren_prep13(
    const float* __restrict__ B2, const float* __restrict__ C2,
    const float* __restrict__ D12, const float* __restrict__ D21,
    const float* __restrict__ St, const float* __restrict__ Q,
    const float* __restrict__ Rinv,
    float* __restrict__ lT1, float* __restrict__ t1,
    float* __restrict__ lT2, float* __restrict__ t2,
    unsigned short* __restrict__ Wvb, unsigned short* __restrict__ C2b,
    unsigned short* __restrict__ D21b)
{
    const int t = threadIdx.x;
    const int blk = blockIdx.x;
    if (blk >= 384) {   // bf16-copy role (uniform branch)
        const int id = (blk - 384) * 64 + t;
        if (id < 16384) {
            Wvb[(id >> 6) * 128 + 64 + (id & 63)] = bf16_rn(D12[id]);
        } else if (id < 16384 + 2048) {
            C2b[id - 16384] = bf16_rn(C2[id - 16384]);
        } else if (id < 16384 + 2048 + 8192) {
            D21b[id - 18432] = bf16_rn(D21[id - 18432]);
        }
        return;
    }

    __shared__ float stl[64 * 33];  // St (64x32), padded
    __shared__ float colbuf[32];    // this block's C2/D21 column
    __shared__ float s1[64];

    const int r = blk;   // 0..383
    const int c = t;     // 0..63
#pragma unroll
    for (int j = 0; j < 32; j++) {
        const int id = j * 64 + t;
        stl[(id >> 5) * 33 + (id & 31)] = St[id];
    }
    if (t < 32)
        colbuf[t] = (r < 64) ? C2[t * 64 + r]
                  : (r < 320 ? D21[t * 256 + (r - 64)] : 0.f);
    __syncthreads();

    float v1;
    if (r < 64) {
        float s = 0.f;
#pragma unroll
        for (int p = 0; p < 32; p++) s += stl[c * 33 + p] * colbuf[p];
        v1 = s;
    } else if (r < 320) {
        float s = 0.f;
#pragma unroll
        for (int p = 0; p < 32; p++) s += stl[c * 33 + p] * colbuf[p];
        v1 = s - D12[(r - 64) * 64 + c];
    } else {
        v1 = B2[(r - 320) * 64 + c];
    }
    s1[c] = v1;
    lT1[r * 64 + c] = v1;
    if (c < 32) {
        const float v2 = (r < 320) ? colbuf[c] : 0.f;
        lT2[r * 32 + c] = v2;
    }
    __syncthreads();

    float a = 0.f;
#pragma unroll
    for (int k = 0; k < 64; k++) a += s1[k] * Rinv[k * 64 + c];
    t1[r * 64 + c] = a;

    if (c < 32) {
        float bq = 0.f;
#pragma unroll
        for (int k = 0; k < 32; k++) bq += colbuf[k] * Q[k * 32 + c];
        t2[r * 32 + c] = bq;
    }
}

// ---------------------------------------------------------------------------
// Prep 2: (unchanged)
// ---------------------------------------------------------------------------
__global__ __launch_bounds__(320) void ren_prep2(
    const float* __restrict__ X,
    const float* __restrict__ lT1, const float* __restrict__ t1,
    const float* __restrict__ lT2, const float* __restrict__ t2,
    unsigned short* __restrict__ Wvb, unsigned short* __restrict__ Drowsb,
    float* __restrict__ Dpair, float* __restrict__ lamg)
{
    __shared__ float xcol[384];
    const int c = threadIdx.x;     // 0..319
    const int i = blockIdx.x;      // 0..255 -> H row 64+i
    for (int t = c; t < 384; t += 320) xcol[t] = X[t * 384 + 64 + i];
    __syncthreads();

    float f0 = 0.f, f1 = 0.f, f2 = 0.f, f3 = 0.f;
    float ac[8], au[8], bc8[8], bu[8];
#pragma unroll
    for (int kk = 0; kk < 8; kk++) { ac[kk] = X[kk * 384 + c]; au[kk] = xcol[kk]; }
    for (int k0 = 0; k0 < 384; k0 += 16) {
#pragma unroll
        for (int kk = 0; kk < 8; kk++) {
            bc8[kk] = X[(k0 + 8 + kk) * 384 + c]; bu[kk] = xcol[k0 + 8 + kk];
        }
        f0 += au[0] * ac[0]; f1 += au[1] * ac[1];
        f2 += au[2] * ac[2]; f3 += au[3] * ac[3];
        f0 += au[4] * ac[4]; f1 += au[5] * ac[5];
        f2 += au[6] * ac[6]; f3 += au[7] * ac[7];
        if (k0 + 16 < 384) {
#pragma unroll
            for (int kk = 0; kk < 8; kk++) {
                ac[kk] = X[(k0 + 16 + kk) * 384 + c]; au[kk] = xcol[k0 + 16 + kk];
            }
        }
        f0 += bu[0] * bc8[0]; f1 += bu[1] * bc8[1];
        f2 += bu[2] * bc8[2]; f3 += bu[3] * bc8[3];
        f0 += bu[4] * bc8[4]; f1 += bu[5] * bc8[5];
        f2 += bu[6] * bc8[6]; f3 += bu[7] * bc8[7];
    }

    const float* __restrict__ t1r = t1 + (64 + i) * 64;
    const float* __restrict__ l1r = lT1 + c * 64;
#pragma unroll
    for (int m4 = 0; m4 < 16; m4++) {
        const float4 lv = *(const float4*)(l1r + m4 * 4);
        f0 += t1r[m4 * 4 + 0] * lv.x; f1 += t1r[m4 * 4 + 1] * lv.y;
        f2 += t1r[m4 * 4 + 2] * lv.z; f3 += t1r[m4 * 4 + 3] * lv.w;
    }
    const float* __restrict__ t2r = t2 + (64 + i) * 32;
    const float* __restrict__ l2r = lT2 + c * 32;
#pragma unroll
    for (int m4 = 0; m4 < 8; m4++) {
        const float4 lv = *(const float4*)(l2r + m4 * 4);
        f0 -= t2r[m4 * 4 + 0] * lv.x; f1 -= t2r[m4 * 4 + 1] * lv.y;
        f2 -= t2r[m4 * 4 + 2] * lv.z; f3 -= t2r[m4 * 4 + 3] * lv.w;
    }
    float acc = (f0 + f1) + (f2 + f3) + (((64 + i) == c) ? 0.001f : 0.f);

    if (c < 64) {
        Wvb[i * 128 + c] = bf16_rn(-acc);       // C_1 = -H_21
    } else {
        const int cb = c - 64;
        if (cb == i) lamg[i] = 5.7707801635558536f / acc;  // (2*log2e)*2/H22ii
        if (i < 255) {
            const float dv = (cb <= i - 1) ? -acc : 0.f;
            Drowsb[(i + 1) * 256 + cb] = bf16_rn(dv);
            const int row = i + 1;
            if ((row >> 4) == (cb >> 4)) {      // diagonal 16-block, pair layout
                const int q = row & 15, p = cb & 15;
                Dpair[(row >> 4) * 256 + (q >> 1) * 32 + p * 2 + (q & 1)] = dv;
            }
        } else {
            Drowsb[cb] = 0;
        }
    }
}

// ---------------------------------------------------------------------------
// Fused two-tile triangle (unchanged): both tiles in one tq loop, shared
// dblk/lam LDS reads, interleaved independent FMA+exp chains.
// ---------------------------------------------------------------------------
__device__ __attribute__((always_inline)) inline void triangle16x2(
    float (&vlA)[16], float (&wlA)[16],
    float (&vlB)[16], float (&wlB)[16],
    const float* __restrict__ dblk, const float* __restrict__ lam)
{
#pragma unroll
    for (int tq = 0; tq < 8; tq++) {
        floatx2 aA, bA, aB, bB;
        aA[0] = vlA[2 * tq]; aA[1] = vlA[2 * tq + 1];
        aB[0] = vlB[2 * tq]; aB[1] = vlB[2 * tq + 1];
        bA[0] = 0.f; bA[1] = 0.f;
        bB[0] = 0.f; bB[1] = 0.f;
#pragma unroll
        for (int p4 = 0; p4 < tq; p4++) {
            const float4 d4 = *(const float4*)&dblk[tq * 32 + p4 * 4];  // LDS, shared
            floatx2 de; de[0] = d4.x; de[1] = d4.y;
            floatx2 dz; dz[0] = d4.z; dz[1] = d4.w;
            aA += de * wlA[2 * p4];  bA += dz * wlA[2 * p4 + 1];
            aB += de * wlB[2 * p4];  bB += dz * wlB[2 * p4 + 1];
        }
        aA += bA; aB += bB;
        floatx2 lm2; lm2[0] = lam[2 * tq]; lm2[1] = lam[2 * tq + 1];  // LDS, shared
        aA *= lm2; aB *= lm2;
        const float e0A = __builtin_amdgcn_exp2f(aA[0]);
        const float e1A = __builtin_amdgcn_exp2f(aA[1]);
        const float e0B = __builtin_amdgcn_exp2f(aB[0]);
        const float e1B = __builtin_amdgcn_exp2f(aB[1]);
        wlA[2 * tq]     = 1.f - 2.f * __builtin_amdgcn_rcpf(e0A + 1.f);
        wlA[2 * tq + 1] = 1.f - 2.f * __builtin_amdgcn_rcpf(e1A + 1.f);
        wlB[2 * tq]     = 1.f - 2.f * __builtin_amdgcn_rcpf(e0B + 1.f);
        wlB[2 * tq + 1] = 1.f - 2.f * __builtin_amdgcn_rcpf(e1B + 1.f);
    }
}

// One pipeline iteration for block nI. R20 ordering: buf/dblk writes ->
// EARLY MFMA (v-GEMM + w-chunks < nI>>1; no dependence on this iter's
// triangle) -> transpose read + triangle (MFMA latency + LDS round-trips
// drain underneath; MFMA and VALU/trans pipes are independent) -> fold ->
// LATE MFMA (just-folded chunk nI>>1 only). Accumulation order per
// accumulator unchanged -> bit-identical. All register-array indices are
// compile-time (predicated full unroll; predicates wave-uniform).
#define REN_ITER(n_, VC, HC, VN, HN, DO_LOAD_)                                 \
  {                                                                            \
    const int nI = (n_);                                                       \
    if (DO_LOAD_) {                                                            \
      const int rb2 = 16 * (nI + 2) + col;                                     \
      _Pragma("unroll") for (int cc = 0; cc < 4; cc++)                         \
        VN[cc] = *(const short8*)(Wvb + rb2 * 128 + cc * 32 + quad * 8);       \
      _Pragma("unroll") for (int cc = 0; cc < 8; cc++)                         \
        HN[cc] = *(const short8*)(Drowsb + rb2 * 256 + cc * 32 + quad * 8);    \
    }                                                                          \
    const float4 dnxtI = *(const float4*)(Dpair + (nI + 1) * 256 + 4 * L);     \
    *(float4*)&dblk[4 * L] = dcur;                                             \
    const float bwvI = bsh[16 * nI + col];                                     \
    _Pragma("unroll") for (int r = 0; r < 4; r++) {                            \
      bufA[quad * 4 + r][col] = accA0[r] + accA1[r] + bwvI;                    \
      bufB[quad * 4 + r][col] = accB0[r] + accB1[r] + bwvI;                    \
    }                                                                          \
    const int lim = (nI + 2) >> 1;   /* chunks 0..lim-1; newest = lim-1 */     \
    floatx4 aA0 = {0.f, 0.f, 0.f, 0.f}, aA1 = {0.f, 0.f, 0.f, 0.f};            \
    floatx4 aB0 = {0.f, 0.f, 0.f, 0.f}, aB1 = {0.f, 0.f, 0.f, 0.f};            \
    aA0 = MFMA16(zfA[0], VC[0], aA0, 0, 0, 0);                                 \
    aB0 = MFMA16(zfB[0], VC[0], aB0, 0, 0, 0);                                 \
    aA1 = MFMA16(zfA[1], VC[1], aA1, 0, 0, 0);                                 \
    aB1 = MFMA16(zfB[1], VC[1], aB1, 0, 0, 0);                                 \
    aA0 = MFMA16(zfA[2], VC[2], aA0, 0, 0, 0);                                 \
    aB0 = MFMA16(zfB[2], VC[2], aB0, 0, 0, 0);                                 \
    aA1 = MFMA16(zfA[3], VC[3], aA1, 0, 0, 0);                                 \
    aB1 = MFMA16(zfB[3], VC[3], aB1, 0, 0, 0);                                 \
    _Pragma("unroll") for (int cc = 0; cc < 7; cc++) {                         \
      if (cc < lim - 1) {          /* older chunks: no triangle(nI) dep */     \
        const short8 wA = wshA[cc * 64 + L];                                   \
        const short8 wB = wshB[cc * 64 + L];                                   \
        if (cc & 1) { aA1 = MFMA16(wA, HC[cc], aA1, 0, 0, 0);                  \
                      aB1 = MFMA16(wB, HC[cc], aB1, 0, 0, 0); }                \
        else        { aA0 = MFMA16(wA, HC[cc], aA0, 0, 0, 0);                  \
                      aB0 = MFMA16(wB, HC[cc], aB0, 0, 0, 0); }                \
      }                                                                        \
    }                                                                          \
    float vlA[16], wlA[16], vlB[16], wlB[16];                                  \
    _Pragma("unroll") for (int p4 = 0; p4 < 4; p4++) {                         \
      const float4 ta = *(const float4*)&bufA[col][p4 * 4];                    \
      const float4 tb = *(const float4*)&bufB[col][p4 * 4];                    \
      vlA[p4 * 4 + 0] = ta.x; vlA[p4 * 4 + 1] = ta.y;                          \
      vlA[p4 * 4 + 2] = ta.z; vlA[p4 * 4 + 3] = ta.w;                          \
      vlB[p4 * 4 + 0] = tb.x; vlB[p4 * 4 + 1] = tb.y;                          \
      vlB[p4 * 4 + 2] = tb.z; vlB[p4 * 4 + 3] = tb.w;                          \
    }                                                                          \
    triangle16x2(vlA, wlA, vlB, wlB, dblk, &lamsh[16 * nI]);                   \
    {                                                                          \
      float4 waA, wbA, waB, wbB;                                               \
      if (quad & 1) {                                                          \
        waA = make_float4(wlA[8], wlA[9], wlA[10], wlA[11]);                   \
        wbA = make_float4(wlA[12], wlA[13], wlA[14], wlA[15]);                 \
        waB = make_float4(wlB[8], wlB[9], wlB[10], wlB[11]);                   \
        wbB = make_float4(wlB[12], wlB[13], wlB[14], wlB[15]);                 \
      } else {                                                                 \
        waA = make_float4(wlA[0], wlA[1], wlA[2], wlA[3]);                     \
        wbA = make_float4(wlA[4], wlA[5], wlA[6], wlA[7]);                     \
        waB = make_float4(wlB[0], wlB[1], wlB[2], wlB[3]);                     \
        wbB = make_float4(wlB[4], wlB[5], wlB[6], wlB[7]);                     \
      }                                                                        \
      const short8 nfA = pack8v(waA, wbA);                                     \
      const short8 nfB = pack8v(waB, wbB);                                     \
      if ((quad >> 1) == (nI & 1)) {                                           \
        wshA[(nI >> 1) * 64 + L] = nfA;                                        \
        wshB[(nI >> 1) * 64 + L] = nfB;                                        \
      }                                                                        \
    }                                                                          \
    _Pragma("unroll") for (int cc = 0; cc < 8; cc++) {                         \
      if (cc == lim - 1) {         /* newest chunk: needs fold(nI) */          \
        const short8 wA = wshA[cc * 64 + L];                                   \
        const short8 wB = wshB[cc * 64 + L];                                   \
        if (cc & 1) { aA1 = MFMA16(wA, HC[cc], aA1, 0, 0, 0);                  \
                      aB1 = MFMA16(wB, HC[cc], aB1, 0, 0, 0); }                \
        else        { aA0 = MFMA16(wA, HC[cc], aA0, 0, 0, 0);                  \
                      aB0 = MFMA16(wB, HC[cc], aB0, 0, 0, 0); }                \
      }                                                                        \
    }                                                                          \
    accA0 = aA0; accA1 = aA1; accB0 = aB0; accB1 = aB1;                        \
    dcur = dnxtI;                                                              \
  }

// ---------------------------------------------------------------------------
// Main — R20 = R19 skeleton (two 16-row tiles/wave, 2-deep operand pipeline)
// with the iteration body re-ordered for dependency-slack overlap (see
// REN_ITER comment). R19's null result falsified the exposed-global-load
// theory; the remaining ~3.7k cyc/iter is serial latency (LDS round-trips,
// MFMA RAW chains, triangle chain) on a 1-wave/SIMD machine — this change
// runs the MFMA phase concurrently with the triangle.
// ---------------------------------------------------------------------------
__global__ __launch_bounds__(64, 1) void ren_main(
    const float* __restrict__ u, const float* __restrict__ x0,
    const float* __restrict__ b,
    const unsigned short* __restrict__ Wvb,
    const unsigned short* __restrict__ Drowsb,
    const float* __restrict__ Dpair,
    const float* __restrict__ lamg,
    const unsigned short* __restrict__ C2b,
    const unsigned short* __restrict__ D21b,
    float* __restrict__ out)
{
    __shared__ float bufA[16][20];  // tile A acc transpose (stride 20)
    __shared__ float bufB[16][20];  // tile B acc transpose
    __shared__ float dblk[256];     // pair-interleaved 16x16 D tile (shared)
    __shared__ float lamsh[256];
    __shared__ float bsh[256];
    __shared__ short8 wshA[8 * 64]; // tile A w A-frags
    __shared__ short8 wshB[8 * 64]; // tile B w A-frags

    const int L = threadIdx.x;
    const int col = L & 15;
    const int quad = L >> 4;
    const int row0 = blockIdx.x * 32;

#pragma unroll
    for (int j = 0; j < 4; j++) {
        lamsh[j * 64 + L] = lamg[j * 64 + L];
        bsh[j * 64 + L]   = b[64 + j * 64 + L];
    }
    const short8 zero8 = {0, 0, 0, 0, 0, 0, 0, 0};
#pragma unroll
    for (int c = 0; c < 8; c++) { wshA[c * 64 + L] = zero8; wshB[c * 64 + L] = zero8; }

    // z A-frags for both tiles: 4 K-chunks of 32 over [x0 | u]
    short8 zfA[4], zfB[4];
#pragma unroll
    for (int c = 0; c < 4; c++) {
        const float* base = (c < 2 ? x0 : u);
        const float* pA = base + (long)(row0 + col) * 64 + (c & 1) * 32 + quad * 8;
        const float* pB = base + (long)(row0 + 16 + col) * 64 + (c & 1) * 32 + quad * 8;
        zfA[c] = pack8v(*(const float4*)pA, *(const float4*)(pA + 4));
        zfB[c] = pack8v(*(const float4*)pB, *(const float4*)(pB + 4));
    }

    // ---- prologue: acc for block 0 (v-GEMM only), shared operands ----
    float4 dcur = *(const float4*)(Dpair + 4 * L);
    floatx4 accA0 = {0.f, 0.f, 0.f, 0.f}, accA1 = {0.f, 0.f, 0.f, 0.f};
    floatx4 accB0 = {0.f, 0.f, 0.f, 0.f}, accB1 = {0.f, 0.f, 0.f, 0.f};
    {
        short8 v0 = *(const short8*)(Wvb + col * 128 + quad * 8);
        short8 v1 = *(const short8*)(Wvb + col * 128 + 32 + quad * 8);
        short8 v2 = *(const short8*)(Wvb + col * 128 + 64 + quad * 8);
        short8 v3 = *(const short8*)(Wvb + col * 128 + 96 + quad * 8);
        accA0 = MFMA16(zfA[0], v0, accA0, 0, 0, 0);
        accB0 = MFMA16(zfB[0], v0, accB0, 0, 0, 0);
        accA1 = MFMA16(zfA[1], v1, accA1, 0, 0, 0);
        accB1 = MFMA16(zfB[1], v1, accB1, 0, 0, 0);
        accA0 = MFMA16(zfA[2], v2, accA0, 0, 0, 0);
        accB0 = MFMA16(zfB[2], v2, accB0, 0, 0, 0);
        accA1 = MFMA16(zfA[3], v3, accA1, 0, 0, 0);
        accB1 = MFMA16(zfB[3], v3, accB1, 0, 0, 0);
    }

    // ---- pipeline prologue: ops(1) -> set 1 ----
    short8 sv0[4], sh0[8], sv1[4], sh1[8];
    {
        const int rb = 16 + col;
#pragma unroll
        for (int c = 0; c < 4; c++)
            sv1[c] = *(const short8*)(Wvb + rb * 128 + c * 32 + quad * 8);
#pragma unroll
        for (int c = 0; c < 8; c++)
            sh1[c] = *(const short8*)(Drowsb + rb * 256 + c * 32 + quad * 8);
    }

    // ---- main loop: pair-unrolled, 2-deep pipelined (iters 0..13) ----
#pragma unroll 1
    for (int np = 0; np < 7; np++) {
        REN_ITER(2 * np,     sv1, sh1, sv0, sh0, 1)   // even: use S1, load S0
        REN_ITER(2 * np + 1, sv0, sh0, sv1, sh1, 1)   // odd:  use S0, load S1
    }
    // ---- iter 14: consume ops(15) from S1; nothing left to load ----
    REN_ITER(14, sv1, sh1, sv0, sh0, 0)

    // ---- peeled n = 15: triangles only (no next block) ----
    {
        *(float4*)&dblk[4 * L] = dcur;
        const float bwv = bsh[240 + col];
#pragma unroll
        for (int r = 0; r < 4; r++) {
            bufA[quad * 4 + r][col] = accA0[r] + accA1[r] + bwv;
            bufB[quad * 4 + r][col] = accB0[r] + accB1[r] + bwv;
        }

        float vlA[16], wlA[16], vlB[16], wlB[16];
#pragma unroll
        for (int p4 = 0; p4 < 4; p4++) {
            const float4 ta = *(const float4*)&bufA[col][p4 * 4];
            const float4 tb = *(const float4*)&bufB[col][p4 * 4];
            vlA[p4 * 4 + 0] = ta.x; vlA[p4 * 4 + 1] = ta.y;
            vlA[p4 * 4 + 2] = ta.z; vlA[p4 * 4 + 3] = ta.w;
            vlB[p4 * 4 + 0] = tb.x; vlB[p4 * 4 + 1] = tb.y;
            vlB[p4 * 4 + 2] = tb.z; vlB[p4 * 4 + 3] = tb.w;
        }

        triangle16x2(vlA, wlA, vlB, wlB, dblk, &lamsh[240]);

        float4 waA, wbA, waB, wbB;
        if (quad & 1) {
            waA = make_float4(wlA[8], wlA[9], wlA[10], wlA[11]);
            wbA = make_float4(wlA[12], wlA[13], wlA[14], wlA[15]);
            waB = make_float4(wlB[8], wlB[9], wlB[10], wlB[11]);
            wbB = make_float4(wlB[12], wlB[13], wlB[14], wlB[15]);
        } else {
            waA = make_float4(wlA[0], wlA[1], wlA[2], wlA[3]);
            wbA = make_float4(wlA[4], wlA[5], wlA[6], wlA[7]);
            waB = make_float4(wlB[0], wlB[1], wlB[2], wlB[3]);
            wbB = make_float4(wlB[4], wlB[5], wlB[6], wlB[7]);
        }
        const short8 nfA = pack8v(waA, wbA);
        const short8 nfB = pack8v(waB, wbB);
        if (quad >= 2) {                  // n=15 odd -> quads 2,3
            wshA[7 * 64 + L] = nfA;
            wshB[7 * 64 + L] = nfB;
        }
    }

    // ---- y phase: Y[16][32] per tile, shared B-operands ----
    floatx4 yA0 = {0.f, 0.f, 0.f, 0.f}, yA1 = {0.f, 0.f, 0.f, 0.f};
    floatx4 yB0 = {0.f, 0.f, 0.f, 0.f}, yB1 = {0.f, 0.f, 0.f, 0.f};
    {
        const short8 yc0 = *(const short8*)(C2b + col * 64 + quad * 8);
        const short8 yc1 = *(const short8*)(C2b + col * 64 + 32 + quad * 8);
        const short8 yc2 = *(const short8*)(C2b + (16 + col) * 64 + quad * 8);
        const short8 yc3 = *(const short8*)(C2b + (16 + col) * 64 + 32 + quad * 8);
        yA0 = MFMA16(zfA[0], yc0, yA0, 0, 0, 0);
        yB0 = MFMA16(zfB[0], yc0, yB0, 0, 0, 0);
        yA1 = MFMA16(zfA[0], yc2, yA1, 0, 0, 0);
        yB1 = MFMA16(zfB[0], yc2, yB1, 0, 0, 0);
        yA0 = MFMA16(zfA[1], yc1, yA0, 0, 0, 0);
        yB0 = MFMA16(zfB[1], yc1, yB0, 0, 0, 0);
        yA1 = MFMA16(zfA[1], yc3, yA1, 0, 0, 0);
        yB1 = MFMA16(zfB[1], yc3, yB1, 0, 0, 0);
    }
#pragma unroll
    for (int c = 0; c < 8; c++) {
        const short8 wA = wshA[c * 64 + L];
        const short8 wB = wshB[c * 64 + L];
        const short8 b0 = *(const short8*)(D21b + col * 256 + c * 32 + quad * 8);
        const short8 b1 = *(const short8*)(D21b + (16 + col) * 256 + c * 32 + quad * 8);
        yA0 = MFMA16(wA, b0, yA0, 0, 0, 0);
        yB0 = MFMA16(wB, b0, yB0, 0, 0, 0);
        yA1 = MFMA16(wA, b1, yA1, 0, 0, 0);
        yB1 = MFMA16(wB, b1, yB1, 0, 0, 0);
    }
    const float by0 = b[320 + col];
    const float by1 = b[336 + col];
#pragma unroll
    for (int r = 0; r < 4; r++) {
        out[(long)(row0 + quad * 4 + r) * 32 + col]           = yA0[r] + by0;
        out[(long)(row0 + quad * 4 + r) * 32 + 16 + col]      = yA1[r] + by1;
        out[(long)(row0 + 16 + quad * 4 + r) * 32 + col]      = yB0[r] + by0;
        out[(long)(row0 + 16 + quad * 4 + r) * 32 + 16 + col] = yB1[r] + by1;
    }
}

// ---------------------------------------------------------------------------
extern "C" void kernel_launch(void* const* d_in, const int* in_sizes, int n_in,
                              void* d_out, int out_size, void* d_ws, size_t ws_size,
                              hipStream_t stream)
{
    const float* u    = (const float*)d_in[0];
    const float* x0   = (const float*)d_in[1];
    const float* B2   = (const float*)d_in[2];
    const float* C2   = (const float*)d_in[3];
    const float* D12  = (const float*)d_in[4];
    const float* D21  = (const float*)d_in[5];
    const float* b    = (const float*)d_in[6];
    const float* X    = (const float*)d_in[7];
    // d_in[8] = Y1 (unused in forward)
    const float* St   = (const float*)d_in[9];
    const float* Q    = (const float*)d_in[10];
    const float* Rinv = (const float*)d_in[11];
    float* out = (float*)d_out;

    float* ws     = (float*)d_ws;
    float* lT1    = ws;                 // 384*64
    float* t1     = lT1 + 384 * 64;     // 384*64
    float* lT2    = t1 + 384 * 64;      // 384*32
    float* t2     = lT2 + 384 * 32;     // 384*32
    float* lamg   = t2 + 384 * 32;      // 256
    float* Dpair  = lamg + 256;         // 16*256 fp32 (pair-interleaved)
    unsigned short* Drowsb = (unsigned short*)(Dpair + 16 * 256); // 256*256
    unsigned short* Wvb    = Drowsb + 256 * 256;                  // 256*128
    unsigned short* C2b    = Wvb + 256 * 128;                     // 32*64
    unsigned short* D21b   = C2b + 32 * 64;                       // 32*256

    ren_prep13<<<dim3(800), dim3(64), 0, stream>>>(B2, C2, D12, D21, St, Q, Rinv,
                                                   lT1, t1, lT2, t2, Wvb, C2b, D21b);
    ren_prep2<<<dim3(256), dim3(320), 0, stream>>>(X, lT1, t1, lT2, t2,
                                                   Wvb, Drowsb, Dpair, lamg);

    const int batch = in_sizes[0] / 64;            // 32768
    ren_main<<<dim3(batch / 32), dim3(64), 0, stream>>>(u, x0, b, Wvb, Drowsb,
                                                        Dpair, lamg, C2b, D21b, out);
}